// Round 1
// baseline (484.905 us; speedup 1.0000x reference)
//
#include <hip/hip_runtime.h>
#include <cstdint>
#include <cstddef>

typedef __bf16 bf16_t;
typedef __bf16 bf16x8 __attribute__((ext_vector_type(8)));
typedef __bf16 bf16x4 __attribute__((ext_vector_type(4)));
typedef float floatx4 __attribute__((ext_vector_type(4)));

#define B_  2
#define T_  2048
#define C_  2048
#define H_  16
#define HD_ 128

// 1/sqrt(128) * log2(e) — folded into Q at QKV-GEMM epilogue
#define K_ATTN_SCALE (0.08838834764831843f * 1.44269504088896f)

// ---- async global->LDS, 16B per lane (m97 recipe) ----
__device__ __forceinline__ void async_copy16(const void* g, void* l) {
  __builtin_amdgcn_global_load_lds((const __attribute__((address_space(1))) unsigned int*)g,
                                   (__attribute__((address_space(3))) unsigned int*)l,
                                   16, 0, 0);
}

// ---------------- convert fp32 -> bf16 (flat) ----------------
__global__ __launch_bounds__(256) void cvt_f32_bf16(const float* __restrict__ in,
                                                    bf16_t* __restrict__ out, int n4) {
  int i = blockIdx.x * 256 + threadIdx.x;
  if (i >= n4) return;
  const float4 v = ((const float4*)in)[i];
  bf16x4 o;
  o[0] = (bf16_t)v.x; o[1] = (bf16_t)v.y; o[2] = (bf16_t)v.z; o[3] = (bf16_t)v.w;
  ((bf16x4*)out)[i] = o;
}

// ------- transpose + convert: W[Kd][Nd] fp32 -> Wt[Nd][Kd] bf16 -------
__global__ __launch_bounds__(256) void transpose_cvt(const float* __restrict__ W,
                                                     bf16_t* __restrict__ Wt,
                                                     int Kd, int Nd) {
  __shared__ float tile[32][33];
  const int tx = threadIdx.x, ty = threadIdx.y;
  const int n0 = blockIdx.x * 32, k0 = blockIdx.y * 32;
#pragma unroll
  for (int j = ty; j < 32; j += 8)
    tile[j][tx] = W[(size_t)(k0 + j) * Nd + n0 + tx];
  __syncthreads();
#pragma unroll
  for (int j = ty; j < 32; j += 8)
    Wt[(size_t)(n0 + j) * Kd + k0 + tx] = (bf16_t)tile[tx][j];
}

// =====================================================================
// QKV GEMM — 256x256 tile, 8 waves, BK=64, 4-phase counted-vmcnt schedule
// (256² 8-phase template, adapted: stages for tile t+1 front-loaded at
//  phase 0 of tile t; single vmcnt(0) at end of phase 3 → ~3.5 phases of
//  flight slack; raw s_barrier, no __syncthreads in the K-loop.)
// LDS: 2 buf × (A 32KB + B 32KB) = 128 KiB, XOR-swizzled (bits 9->5,10->4).
// =====================================================================
#define GBM 256
#define GBN 256
#define GBK 64

__global__ __launch_bounds__(512, 2) void gemm_qkv(
    const bf16_t* __restrict__ A, const bf16_t* __restrict__ Bt,
    const float* __restrict__ bias,
    bf16_t* __restrict__ Qo, bf16_t* __restrict__ Ko, bf16_t* __restrict__ Vo,
    int K) {
  __shared__ __align__(16) char smem[131072];
  const int tid = threadIdx.x;
  const int wave = tid >> 6, lane = tid & 63;
  const int quad = lane >> 4, l15 = lane & 15;
  const int wm = wave >> 2, wn = wave & 3;
  const int bm = blockIdx.y * GBM, bn = blockIdx.x * GBN;

  // ---- staging map: linear LDS dest <- inverse-swizzled global source ----
  // within a 32KB operand tile: LDS byte p = l*8192 + tid*16
  const bf16_t* asrc[4];
  const bf16_t* bsrc[4];
#pragma unroll
  for (int l = 0; l < 4; ++l) {
    int p = l * 8192 + tid * 16;
    int q = p ^ (((p >> 9) & 1) << 5) ^ (((p >> 10) & 1) << 4);  // involution
    int r = q >> 7, c8 = (q >> 4) & 7;
    asrc[l] = A  + (size_t)(bm + r) * K + c8 * 8;
    bsrc[l] = Bt + (size_t)(bn + r) * K + c8 * 8;
  }

  auto stage = [&](int buf, int k0) {
    char* As = smem + buf * 65536;
    char* Bs = As + 32768;
#pragma unroll
    for (int l = 0; l < 4; ++l) {
      int p = l * 8192 + tid * 16;
      async_copy16(asrc[l] + k0, As + p);
      async_copy16(bsrc[l] + k0, Bs + p);
    }
  };

  // ---- read-side swizzle: byte col ^= ((row&4)<<3) | ((row&8)<<1);
  //      row&4 == l15&4 and row&8 == l15&8 for all fragment rows -> per-thread const
  const int sx = ((l15 & 4) << 3) | ((l15 & 8) << 1);
  const int cq = quad * 16;                 // fragment col base (bytes)
  const int arow = (wm * 128 + l15) << 7;   // A row base (bytes), + mq*64 + i*16 rows
  const int brow = (wn * 64 + l15) << 7;    // B row base (bytes), + nq*32 + j*16 rows

  floatx4 acc[8][4] = {};

  stage(0, 0);
  asm volatile("s_waitcnt vmcnt(0)" ::: "memory");
  __builtin_amdgcn_s_barrier();

  const int NT = K / GBK;
  for (int t = 0; t < NT; ++t) {
    const int buf = t & 1;
    const char* As = smem + buf * 65536;
    const char* Bs = As + 32768;
    if (t + 1 < NT) stage(buf ^ 1, (t + 1) * GBK);  // earliest WAR-safe point

#pragma unroll
    for (int mq = 0; mq < 2; ++mq) {
      bf16x8 af[4][2];
#pragma unroll
      for (int i = 0; i < 4; ++i)
#pragma unroll
        for (int ks = 0; ks < 2; ++ks)
          af[i][ks] = *(const bf16x8*)(As + arow + (((mq * 64 + i * 16)) << 7) +
                                       ((ks * 64 + cq) ^ sx));
#pragma unroll
      for (int nq = 0; nq < 2; ++nq) {
        bf16x8 bfr[2][2];
#pragma unroll
        for (int j = 0; j < 2; ++j)
#pragma unroll
          for (int ks = 0; ks < 2; ++ks)
            bfr[j][ks] = *(const bf16x8*)(Bs + brow + (((nq * 32 + j * 16)) << 7) +
                                          ((ks * 64 + cq) ^ sx));
        __builtin_amdgcn_s_barrier();
        __builtin_amdgcn_s_setprio(1);
#pragma unroll
        for (int i = 0; i < 4; ++i)
#pragma unroll
          for (int j = 0; j < 2; ++j)
#pragma unroll
            for (int ks = 0; ks < 2; ++ks)
              acc[mq * 4 + i][nq * 2 + j] = __builtin_amdgcn_mfma_f32_16x16x32_bf16(
                  af[i][ks], bfr[j][ks], acc[mq * 4 + i][nq * 2 + j], 0, 0, 0);
        __builtin_amdgcn_s_setprio(0);
        if (mq == 1 && nq == 1)  // once per tile: next tile's loads had ~3.5 phases to fly
          asm volatile("s_waitcnt vmcnt(0)" ::: "memory");
        __builtin_amdgcn_s_barrier();
      }
    }
  }

  // ---------------- epilogue ----------------
  float bias_r[4];
#pragma unroll
  for (int jj = 0; jj < 4; ++jj)
    bias_r[jj] = bias[bn + wn * 64 + (jj >> 1) * 32 + (jj & 1) * 16 + l15];

  if (bn < 2 * C_) {
    // ---- Q / K scatter to [B,H,T,hd] ----
    const int which = bn >> 11;  // 0 = Q, 1 = K (uniform per block)
    bf16_t* dst0 = which ? Ko : Qo;
    const float scl = which ? 1.0f : K_ATTN_SCALE;
#pragma unroll
    for (int ii = 0; ii < 8; ++ii) {
      const int m = bm + wm * 128 + (ii >> 2) * 64 + (ii & 3) * 16 + quad * 4;
      const int b = m >> 11, tq = m & 2047;
#pragma unroll
      for (int jj = 0; jj < 4; ++jj) {
        const int n = bn + wn * 64 + (jj >> 1) * 32 + (jj & 1) * 16 + l15;
        const int cc = n & 2047;
        const int h = cc >> 7, d = cc & 127;
        bf16_t* dst = dst0 + (((size_t)(b * H_ + h)) * T_ + tq) * HD_ + d;
#pragma unroll
        for (int r = 0; r < 4; ++r)
          dst[(size_t)r * HD_] = (bf16_t)((acc[ii][jj][r] + bias_r[jj]) * scl);
      }
    }
  } else {
    // ---- V block: transpose 256x256 tile through LDS (exactly 128 KiB) ----
    __syncthreads();  // all waves fully past main-loop LDS reads
    bf16_t* vt = (bf16_t*)smem;
#pragma unroll
    for (int ii = 0; ii < 8; ++ii) {
      const int tl = wm * 128 + (ii >> 2) * 64 + (ii & 3) * 16 + quad * 4;
#pragma unroll
      for (int jj = 0; jj < 4; ++jj) {
        const int dl = wn * 64 + (jj >> 1) * 32 + (jj & 1) * 16 + l15;
        const int sw = 8 * (dl & 15);
#pragma unroll
        for (int r = 0; r < 4; ++r)
          vt[dl * 256 + ((tl + r) ^ sw)] = (bf16_t)(acc[ii][jj][r] + bias_r[jj]);
      }
    }
    __syncthreads();
    const int dr = tid >> 1, half = tid & 1;
    const int h = ((bn - 2 * C_) >> 7) + (dr >> 7);
    const int b = bm >> 11, t0g = bm & 2047;
    bf16_t* dst = Vo + ((size_t)(b * H_ + h) * HD_ + (dr & 127)) * T_ + t0g;
#pragma unroll
    for (int cc2 = 0; cc2 < 16; ++cc2) {
      const int c = half * 16 + cc2;
      uint4 v = *(const uint4*)&vt[dr * 256 + ((c ^ (dr & 15)) * 8)];
      *(uint4*)(dst + c * 8) = v;
    }
  }
}

// ---------------- proj GEMM (m97 structure + XOR-swizzled LDS, fp32 out) ----------------
#define TM 128
#define TN 128
#define BK 64

__global__ __launch_bounds__(256) void gemm_proj(
    const bf16_t* __restrict__ A, const bf16_t* __restrict__ Bt,
    const float* __restrict__ bias, float* __restrict__ Cout,
    int M, int N, int K) {
  __shared__ __align__(16) char smem[32768];
  bf16_t (*As)[BK] = (bf16_t(*)[BK])smem;              // 16 KB
  bf16_t (*Bs)[BK] = (bf16_t(*)[BK])(smem + 16384);    // 16 KB
  const int tid = threadIdx.x;
  const int wave = tid >> 6, lane = tid & 63;
  const int quad = lane >> 4, l15 = lane & 15;
  const int bm = blockIdx.y * TM, bn = blockIdx.x * TN;
  const int wm = (wave >> 1) * 64, wn = (wave & 1) * 64;
  const int sw = l15 & 7;   // read-side swizzle

  floatx4 acc[4][4] = {};

  for (int k0 = 0; k0 < K; k0 += BK) {
#pragma unroll
    for (int it = 0; it < 4; ++it) {
      int p = it * 4096 + tid * 16;      // LDS byte offset (lane-linear)
      int r = p >> 7;                    // tile row
      int cg = ((p >> 4) & 7) ^ (r & 7); // global chunk held by this slot
      async_copy16(A + (size_t)(bm + r) * K + k0 + cg * 8, (char*)&As[0][0] + p);
      async_copy16(Bt + (size_t)(bn + r) * K + k0 + cg * 8, (char*)&Bs[0][0] + p);
    }
    __syncthreads();
#pragma unroll
    for (int kc = 0; kc < 2; ++kc) {
      const int cidx = (kc * 4 + quad) ^ sw;
      bf16x8 af[4], bf[4];
#pragma unroll
      for (int i = 0; i < 4; ++i)
        af[i] = *(const bf16x8*)&As[wm + i * 16 + l15][cidx * 8];
#pragma unroll
      for (int j = 0; j < 4; ++j)
        bf[j] = *(const bf16x8*)&Bs[wn + j * 16 + l15][cidx * 8];
#pragma unroll
      for (int i = 0; i < 4; ++i)
#pragma unroll
        for (int j = 0; j < 4; ++j)
          acc[i][j] = __builtin_amdgcn_mfma_f32_16x16x32_bf16(af[i], bf[j], acc[i][j], 0, 0, 0);
    }
    __syncthreads();
  }

#pragma unroll
  for (int i = 0; i < 4; ++i) {
#pragma unroll
    for (int j = 0; j < 4; ++j) {
#pragma unroll
      for (int r = 0; r < 4; ++r) {
        int m = bm + wm + i * 16 + quad * 4 + r;
        int n = bn + wn + j * 16 + l15;
        Cout[(size_t)m * N + n] = acc[i][j][r] + bias[n];
      }
    }
  }
}

// ---------------- causal flash attention (double-buffered K/V staging) ----------------
__global__ __launch_bounds__(256) void attn(const bf16_t* __restrict__ Q,
                                            const bf16_t* __restrict__ Kg,
                                            const bf16_t* __restrict__ Vt,
                                            bf16_t* __restrict__ O) {
  __shared__ bf16_t Ks[2][64][128];   // rows 256B=16 chunks; chunk c of row r at c^(r&15)
  __shared__ bf16_t Vs[2][128][64];   // rows 128B=8 chunks;  chunk c of row r at c^(r&7)
  const int tid = threadIdx.x;
  const int wave = tid >> 6, lane = tid & 63;
  const int quad = lane >> 4, l15 = lane & 15;
  const int j = blockIdx.x;        // 0..15
  const int bh = blockIdx.y;
  const int b = bh >> 4, h = bh & 15;
  const int qtA = 31 - j, qtB = j;           // heavy, light
  const int nchA = qtA + 1, nchB = qtB + 1;
  const int q0A = qtA * 64 + wave * 16;
  const int q0B = qtB * 64 + wave * 16;

  const bf16_t* Qh = Q + (size_t)bh * T_ * HD_;
  const bf16_t* Kh = Kg + (size_t)bh * T_ * HD_;
  const bf16_t* Vh = Vt + (size_t)bh * HD_ * T_;

  bf16x8 qfA[4], qfB[4];
#pragma unroll
  for (int kk = 0; kk < 4; ++kk) {
    qfA[kk] = *(const bf16x8*)(Qh + (size_t)(q0A + l15) * HD_ + kk * 32 + quad * 8);
    qfB[kk] = *(const bf16x8*)(Qh + (size_t)(q0B + l15) * HD_ + kk * 32 + quad * 8);
  }

  floatx4 oaccA[8] = {}, oaccB[8] = {};
  float l_A = 0.0f, l_B = 0.0f;

  union PU { bf16x4 v; long long u; };
  union PF { long long u[2]; bf16x8 v; };
  const int lo = ((lane & 16) << 1) + l15;  // (quad&1)*32 + l15

  auto stage = [&](int buf, int kt0) {
#pragma unroll
    for (int it = 0; it < 4; ++it) {
      int p = it * 4096 + tid * 16;
      int r = p >> 8;
      int cg = ((p >> 4) & 15) ^ (r & 15);
      async_copy16(Kh + (size_t)(kt0 + r) * HD_ + cg * 8, (char*)&Ks[buf][0][0] + p);
    }
#pragma unroll
    for (int it = 0; it < 4; ++it) {
      int p = it * 4096 + tid * 16;
      int r = p >> 7;
      int cg = ((p >> 4) & 7) ^ (r & 7);
      async_copy16(Vh + (size_t)r * T_ + kt0 + cg * 8, (char*)&Vs[buf][0][0] + p);
    }
  };

  auto step = [&](int buf, const bf16x8* qf, floatx4* oacc, float& l_i, int q0, int kt0,
                  bool mask) {
    floatx4 s[4] = {{}, {}, {}, {}};
#pragma unroll
    for (int st = 0; st < 4; ++st) {
#pragma unroll
      for (int kk = 0; kk < 4; ++kk) {
        bf16x8 kf = *(const bf16x8*)&Ks[buf][st * 16 + l15][(((kk * 4 + quad) ^ l15) & 15) * 8];
        s[st] = __builtin_amdgcn_mfma_f32_16x16x32_bf16(kf, qf[kk], s[st], 0, 0, 0);
      }
    }
    float ps = 0.0f;
    long long pu[4];
#pragma unroll
    for (int st = 0; st < 4; ++st) {
      PU t;
#pragma unroll
      for (int r = 0; r < 4; ++r) {
        float val = s[st][r];
        if (mask) {
          int kt = kt0 + st * 16 + quad * 4 + r;
          val = (kt <= q0 + l15) ? val : -3.0e38f;
        }
        float p = exp2f(val);
        ps += p;
        t.v[r] = (bf16_t)p;
      }
      pu[st] = t.u;
    }
    ps += __shfl_xor(ps, 16);
    ps += __shfl_xor(ps, 32);
    l_i += ps;
#pragma unroll
    for (int bb = 0; bb < 2; ++bb) {
      long long lo0 = __shfl(pu[2 * bb], lo);
      long long hi0 = __shfl(pu[2 * bb], lo + 16);
      long long lo1 = __shfl(pu[2 * bb + 1], lo);
      long long hi1 = __shfl(pu[2 * bb + 1], lo + 16);
      PF pf;
      pf.u[0] = (quad >= 2) ? lo1 : lo0;
      pf.u[1] = (quad >= 2) ? hi1 : hi0;
#pragma unroll
      for (int dt = 0; dt < 8; ++dt) {
        bf16x8 vf = *(const bf16x8*)&Vs[buf][dt * 16 + l15][(((bb * 4 + quad) ^ l15) & 7) * 8];
        oacc[dt] = __builtin_amdgcn_mfma_f32_16x16x32_bf16(pf.v, vf, oacc[dt], 0, 0, 0);
      }
    }
  };

  stage(0, 0);
  for (int ch = 0; ch < nchA; ++ch) {
    __syncthreads();
    if (ch + 1 < nchA) stage((ch + 1) & 1, (ch + 1) * 64);  // fly during compute
    const int kt0 = ch * 64;
    const int buf = ch & 1;
    step(buf, qfA, oaccA, l_A, q0A, kt0, ch == nchA - 1);
    if (ch < nchB) step(buf, qfB, oaccB, l_B, q0B, kt0, ch == nchB - 1);
  }

  float lrA[4], lrB[4];
#pragma unroll
  for (int r = 0; r < 4; ++r) {
    lrA[r] = __shfl(l_A, quad * 4 + r);
    lrB[r] = __shfl(l_B, quad * 4 + r);
  }
#pragma unroll
  for (int dt = 0; dt < 8; ++dt) {
#pragma unroll
    for (int r = 0; r < 4; ++r) {
      int d = dt * 16 + l15;
      int qa = q0A + quad * 4 + r;
      int qb = q0B + quad * 4 + r;
      O[((size_t)(b * T_ + qa)) * C_ + h * HD_ + d] = (bf16_t)(oaccA[dt][r] / lrA[r]);
      O[((size_t)(b * T_ + qb)) * C_ + h * HD_ + d] = (bf16_t)(oaccB[dt][r] / lrB[r]);
    }
  }
}

// ---------------- launch ----------------
extern "C" void kernel_launch(void* const* d_in, const int* in_sizes, int n_in,
                              void* d_out, int out_size, void* d_ws, size_t ws_size,
                              hipStream_t stream) {
  const float* x      = (const float*)d_in[0];
  const float* w_attn = (const float*)d_in[1];
  const float* b_attn = (const float*)d_in[2];
  const float* w_proj = (const float*)d_in[3];
  const float* b_proj = (const float*)d_in[4];
  float* out = (float*)d_out;

  char* p = (char*)d_ws;
  bf16_t* xb  = (bf16_t*)p; p += (size_t)4096 * 2048 * 2;      // x bf16 [B*T][C]
  bf16_t* waT = (bf16_t*)p; p += (size_t)6144 * 2048 * 2;      // w_attn^T bf16 [3C][C]
  bf16_t* wpT = (bf16_t*)p; p += (size_t)2048 * 2048 * 2;      // w_proj^T bf16 [C][C]
  bf16_t* Qb  = (bf16_t*)p; p += (size_t)32 * 2048 * 128 * 2;  // [B,H,T,hd] (pre-scaled)
  bf16_t* Kb  = (bf16_t*)p; p += (size_t)32 * 2048 * 128 * 2;  // [B,H,T,hd]
  bf16_t* Vb  = (bf16_t*)p; p += (size_t)32 * 2048 * 128 * 2;  // [B,H,hd,T] (transposed)
  bf16_t* Ob  = (bf16_t*)p; p += (size_t)4096 * 2048 * 2;      // attn out bf16 [B*T][C]

  cvt_f32_bf16<<<8192, 256, 0, stream>>>(x, xb, 2097152);
  transpose_cvt<<<dim3(6144 / 32, 2048 / 32), dim3(32, 8), 0, stream>>>(w_attn, waT, 2048, 6144);
  transpose_cvt<<<dim3(2048 / 32, 2048 / 32), dim3(32, 8), 0, stream>>>(w_proj, wpT, 2048, 2048);

  gemm_qkv<<<dim3(6144 / GBN, 4096 / GBM), 512, 0, stream>>>(
      xb, waT, b_attn, Qb, Kb, Vb, 2048);

  attn<<<dim3(16, 32), 256, 0, stream>>>(Qb, Kb, Vb, Ob);

  gemm_proj<<<dim3(2048 / TN, 4096 / TM), 256, 0, stream>>>(
      Ob, wpT, b_proj, out, 4096, 2048, 2048);
}

// Round 2
// 429.693 us; speedup vs baseline: 1.1285x; 1.1285x over previous
//
#include <hip/hip_runtime.h>
#include <cstdint>
#include <cstddef>

typedef __bf16 bf16_t;
typedef __bf16 bf16x8 __attribute__((ext_vector_type(8)));
typedef __bf16 bf16x4 __attribute__((ext_vector_type(4)));
typedef float floatx4 __attribute__((ext_vector_type(4)));

#define B_  2
#define T_  2048
#define C_  2048
#define H_  16
#define HD_ 128

// 1/sqrt(128) * log2(e) — folded into Q at QKV-GEMM epilogue
#define K_ATTN_SCALE (0.08838834764831843f * 1.44269504088896f)

// ---- async global->LDS, 16B per lane (m97 recipe) ----
__device__ __forceinline__ void async_copy16(const void* g, void* l) {
  __builtin_amdgcn_global_load_lds((const __attribute__((address_space(1))) unsigned int*)g,
                                   (__attribute__((address_space(3))) unsigned int*)l,
                                   16, 0, 0);
}

// ---------------- convert fp32 -> bf16 (flat) ----------------
__global__ __launch_bounds__(256) void cvt_f32_bf16(const float* __restrict__ in,
                                                    bf16_t* __restrict__ out, int n4) {
  int i = blockIdx.x * 256 + threadIdx.x;
  if (i >= n4) return;
  const float4 v = ((const float4*)in)[i];
  bf16x4 o;
  o[0] = (bf16_t)v.x; o[1] = (bf16_t)v.y; o[2] = (bf16_t)v.z; o[3] = (bf16_t)v.w;
  ((bf16x4*)out)[i] = o;
}

// ------- transpose + convert: W[Kd][Nd] fp32 -> Wt[Nd][Kd] bf16 -------
__global__ __launch_bounds__(256) void transpose_cvt(const float* __restrict__ W,
                                                     bf16_t* __restrict__ Wt,
                                                     int Kd, int Nd) {
  __shared__ float tile[32][33];
  const int tx = threadIdx.x, ty = threadIdx.y;
  const int n0 = blockIdx.x * 32, k0 = blockIdx.y * 32;
#pragma unroll
  for (int j = ty; j < 32; j += 8)
    tile[j][tx] = W[(size_t)(k0 + j) * Nd + n0 + tx];
  __syncthreads();
#pragma unroll
  for (int j = ty; j < 32; j += 8)
    Wt[(size_t)(n0 + j) * Kd + k0 + tx] = (bf16_t)tile[tx][j];
}

// =====================================================================
// QKV GEMM — 256x256 tile, 8 waves, BK=64, 4-phase counted-vmcnt schedule.
// LDS: 2 buf × (A 32KB + B 32KB) = 128 KiB.
// Swizzle (T2, 3-bit): physical (r, c) holds logical (r, c ^ ((r&7)<<4)).
// Each 16B slot s of row r holds logical slot s ^ (r&7) -> lanes 0..7 of a
// ds_read_b128 group cover all 8 slots (2-way residual = free, m136).
// =====================================================================
#define GBM 256
#define GBN 256
#define GBK 64

__global__ __launch_bounds__(512, 2) void gemm_qkv(
    const bf16_t* __restrict__ A, const bf16_t* __restrict__ Bt,
    const float* __restrict__ bias,
    bf16_t* __restrict__ Qo, bf16_t* __restrict__ Ko, bf16_t* __restrict__ Vo,
    int K) {
  __shared__ __align__(16) char smem[131072];
  const int tid = threadIdx.x;
  const int wave = tid >> 6, lane = tid & 63;
  const int quad = lane >> 4, l15 = lane & 15;
  const int wm = wave >> 2, wn = wave & 3;
  const int bm = blockIdx.y * GBM, bn = blockIdx.x * GBN;

  // ---- staging map: linear LDS dest <- inverse-swizzled global source ----
  // within a 32KB operand tile: LDS byte p = l*8192 + tid*16
  const bf16_t* asrc[4];
  const bf16_t* bsrc[4];
#pragma unroll
  for (int l = 0; l < 4; ++l) {
    int p = l * 8192 + tid * 16;
    int r = p >> 7;                           // tile row (0..255)
    int c = (p & 127) ^ ((r & 7) << 4);       // logical col byte held at p
    asrc[l] = A  + (size_t)(bm + r) * K + (c >> 1);
    bsrc[l] = Bt + (size_t)(bn + r) * K + (c >> 1);
  }

  auto stage = [&](int buf, int k0) {
    char* As = smem + buf * 65536;
    char* Bs = As + 32768;
#pragma unroll
    for (int l = 0; l < 4; ++l) {
      int p = l * 8192 + tid * 16;
      async_copy16(asrc[l] + k0, As + p);
      async_copy16(bsrc[l] + k0, Bs + p);
    }
  };

  // ---- read-side swizzle: col byte ^= ((row&7)<<4); row&7 == l15&7 for all
  //      fragment rows -> per-thread constant.
  const int sx = (l15 & 7) << 4;
  const int cq = quad * 16;                 // fragment col base (bytes)
  const int arow = (wm * 128 + l15) << 7;   // A row base (bytes), + mq*64 + i*16 rows
  const int brow = (wn * 64 + l15) << 7;    // B row base (bytes), + nq*32 + j*16 rows

  floatx4 acc[8][4] = {};

  stage(0, 0);
  asm volatile("s_waitcnt vmcnt(0)" ::: "memory");
  __builtin_amdgcn_s_barrier();

  const int NT = K / GBK;
  for (int t = 0; t < NT; ++t) {
    const int buf = t & 1;
    const char* As = smem + buf * 65536;
    const char* Bs = As + 32768;
    if (t + 1 < NT) stage(buf ^ 1, (t + 1) * GBK);  // earliest WAR-safe point

#pragma unroll
    for (int mq = 0; mq < 2; ++mq) {
      bf16x8 af[4][2];
#pragma unroll
      for (int i = 0; i < 4; ++i)
#pragma unroll
        for (int ks = 0; ks < 2; ++ks)
          af[i][ks] = *(const bf16x8*)(As + arow + (((mq * 64 + i * 16)) << 7) +
                                       ((ks * 64 + cq) ^ sx));
#pragma unroll
      for (int nq = 0; nq < 2; ++nq) {
        bf16x8 bfr[2][2];
#pragma unroll
        for (int j = 0; j < 2; ++j)
#pragma unroll
          for (int ks = 0; ks < 2; ++ks)
            bfr[j][ks] = *(const bf16x8*)(Bs + brow + (((nq * 32 + j * 16)) << 7) +
                                          ((ks * 64 + cq) ^ sx));
        __builtin_amdgcn_s_barrier();
        __builtin_amdgcn_s_setprio(1);
#pragma unroll
        for (int i = 0; i < 4; ++i)
#pragma unroll
          for (int j = 0; j < 2; ++j)
#pragma unroll
            for (int ks = 0; ks < 2; ++ks)
              acc[mq * 4 + i][nq * 2 + j] = __builtin_amdgcn_mfma_f32_16x16x32_bf16(
                  af[i][ks], bfr[j][ks], acc[mq * 4 + i][nq * 2 + j], 0, 0, 0);
        __builtin_amdgcn_s_setprio(0);
        if (mq == 1 && nq == 1)  // once per tile: next tile's loads had ~3.5 phases to fly
          asm volatile("s_waitcnt vmcnt(0)" ::: "memory");
        __builtin_amdgcn_s_barrier();
      }
    }
  }

  // ---------------- epilogue ----------------
  float bias_r[4];
#pragma unroll
  for (int jj = 0; jj < 4; ++jj)
    bias_r[jj] = bias[bn + wn * 64 + (jj >> 1) * 32 + (jj & 1) * 16 + l15];

  if (bn < 2 * C_) {
    // ---- Q / K scatter to [B,H,T,hd] ----
    const int which = bn >> 11;  // 0 = Q, 1 = K (uniform per block)
    bf16_t* dst0 = which ? Ko : Qo;
    const float scl = which ? 1.0f : K_ATTN_SCALE;
#pragma unroll
    for (int ii = 0; ii < 8; ++ii) {
      const int m = bm + wm * 128 + (ii >> 2) * 64 + (ii & 3) * 16 + quad * 4;
      const int b = m >> 11, tq = m & 2047;
#pragma unroll
      for (int jj = 0; jj < 4; ++jj) {
        const int n = bn + wn * 64 + (jj >> 1) * 32 + (jj & 1) * 16 + l15;
        const int cc = n & 2047;
        const int h = cc >> 7, d = cc & 127;
        bf16_t* dst = dst0 + (((size_t)(b * H_ + h)) * T_ + tq) * HD_ + d;
#pragma unroll
        for (int r = 0; r < 4; ++r)
          dst[(size_t)r * HD_] = (bf16_t)((acc[ii][jj][r] + bias_r[jj]) * scl);
      }
    }
  } else {
    // ---- V block: transpose 256x256 tile through LDS (exactly 128 KiB) ----
    __syncthreads();  // all waves fully past main-loop LDS reads
    bf16_t* vt = (bf16_t*)smem;
#pragma unroll
    for (int ii = 0; ii < 8; ++ii) {
      const int tl = wm * 128 + (ii >> 2) * 64 + (ii & 3) * 16 + quad * 4;
#pragma unroll
      for (int jj = 0; jj < 4; ++jj) {
        const int dl = wn * 64 + (jj >> 1) * 32 + (jj & 1) * 16 + l15;
        const int sw = 8 * (dl & 15);
#pragma unroll
        for (int r = 0; r < 4; ++r)
          vt[dl * 256 + ((tl + r) ^ sw)] = (bf16_t)(acc[ii][jj][r] + bias_r[jj]);
      }
    }
    __syncthreads();
    const int dr = tid >> 1, half = tid & 1;
    const int h = ((bn - 2 * C_) >> 7) + (dr >> 7);
    const int b = bm >> 11, t0g = bm & 2047;
    bf16_t* dst = Vo + ((size_t)(b * H_ + h) * HD_ + (dr & 127)) * T_ + t0g;
#pragma unroll
    for (int cc2 = 0; cc2 < 16; ++cc2) {
      const int c = half * 16 + cc2;
      uint4 v = *(const uint4*)&vt[dr * 256 + ((c ^ (dr & 15)) * 8)];
      *(uint4*)(dst + c * 8) = v;
    }
  }
}

// ---------------- proj GEMM (m97 structure + XOR-swizzled LDS, fp32 out) ----------------
#define TM 128
#define TN 128
#define BK 64

__global__ __launch_bounds__(256) void gemm_proj(
    const bf16_t* __restrict__ A, const bf16_t* __restrict__ Bt,
    const float* __restrict__ bias, float* __restrict__ Cout,
    int M, int N, int K) {
  __shared__ __align__(16) char smem[32768];
  bf16_t (*As)[BK] = (bf16_t(*)[BK])smem;              // 16 KB
  bf16_t (*Bs)[BK] = (bf16_t(*)[BK])(smem + 16384);    // 16 KB
  const int tid = threadIdx.x;
  const int wave = tid >> 6, lane = tid & 63;
  const int quad = lane >> 4, l15 = lane & 15;
  const int bm = blockIdx.y * TM, bn = blockIdx.x * TN;
  const int wm = (wave >> 1) * 64, wn = (wave & 1) * 64;
  const int sw = l15 & 7;   // read-side swizzle

  floatx4 acc[4][4] = {};

  for (int k0 = 0; k0 < K; k0 += BK) {
#pragma unroll
    for (int it = 0; it < 4; ++it) {
      int p = it * 4096 + tid * 16;      // LDS byte offset (lane-linear)
      int r = p >> 7;                    // tile row
      int cg = ((p >> 4) & 7) ^ (r & 7); // global chunk held by this slot
      async_copy16(A + (size_t)(bm + r) * K + k0 + cg * 8, (char*)&As[0][0] + p);
      async_copy16(Bt + (size_t)(bn + r) * K + k0 + cg * 8, (char*)&Bs[0][0] + p);
    }
    __syncthreads();
#pragma unroll
    for (int kc = 0; kc < 2; ++kc) {
      const int cidx = (kc * 4 + quad) ^ sw;
      bf16x8 af[4], bf[4];
#pragma unroll
      for (int i = 0; i < 4; ++i)
        af[i] = *(const bf16x8*)&As[wm + i * 16 + l15][cidx * 8];
#pragma unroll
      for (int j = 0; j < 4; ++j)
        bf[j] = *(const bf16x8*)&Bs[wn + j * 16 + l15][cidx * 8];
#pragma unroll
      for (int i = 0; i < 4; ++i)
#pragma unroll
        for (int j = 0; j < 4; ++j)
          acc[i][j] = __builtin_amdgcn_mfma_f32_16x16x32_bf16(af[i], bf[j], acc[i][j], 0, 0, 0);
    }
    __syncthreads();
  }

#pragma unroll
  for (int i = 0; i < 4; ++i) {
#pragma unroll
    for (int j = 0; j < 4; ++j) {
#pragma unroll
      for (int r = 0; r < 4; ++r) {
        int m = bm + wm + i * 16 + quad * 4 + r;
        int n = bn + wn + j * 16 + l15;
        Cout[(size_t)m * N + n] = acc[i][j][r] + bias[n];
      }
    }
  }
}

// ---------------- causal flash attention (double-buffered K/V staging) ----------------
__global__ __launch_bounds__(256) void attn(const bf16_t* __restrict__ Q,
                                            const bf16_t* __restrict__ Kg,
                                            const bf16_t* __restrict__ Vt,
                                            bf16_t* __restrict__ O) {
  __shared__ bf16_t Ks[2][64][128];   // rows 256B=16 chunks; chunk c of row r at c^(r&15)
  __shared__ bf16_t Vs[2][128][64];   // rows 128B=8 chunks;  chunk c of row r at c^(r&7)
  const int tid = threadIdx.x;
  const int wave = tid >> 6, lane = tid & 63;
  const int quad = lane >> 4, l15 = lane & 15;
  const int j = blockIdx.x;        // 0..15
  const int bh = blockIdx.y;
  const int b = bh >> 4, h = bh & 15;
  const int qtA = 31 - j, qtB = j;           // heavy, light
  const int nchA = qtA + 1, nchB = qtB + 1;
  const int q0A = qtA * 64 + wave * 16;
  const int q0B = qtB * 64 + wave * 16;

  const bf16_t* Qh = Q + (size_t)bh * T_ * HD_;
  const bf16_t* Kh = Kg + (size_t)bh * T_ * HD_;
  const bf16_t* Vh = Vt + (size_t)bh * HD_ * T_;

  bf16x8 qfA[4], qfB[4];
#pragma unroll
  for (int kk = 0; kk < 4; ++kk) {
    qfA[kk] = *(const bf16x8*)(Qh + (size_t)(q0A + l15) * HD_ + kk * 32 + quad * 8);
    qfB[kk] = *(const bf16x8*)(Qh + (size_t)(q0B + l15) * HD_ + kk * 32 + quad * 8);
  }

  floatx4 oaccA[8] = {}, oaccB[8] = {};
  float l_A = 0.0f, l_B = 0.0f;

  union PU { bf16x4 v; long long u; };
  union PF { long long u[2]; bf16x8 v; };
  const int lo = ((lane & 16) << 1) + l15;  // (quad&1)*32 + l15

  auto stage = [&](int buf, int kt0) {
#pragma unroll
    for (int it = 0; it < 4; ++it) {
      int p = it * 4096 + tid * 16;
      int r = p >> 8;
      int cg = ((p >> 4) & 15) ^ (r & 15);
      async_copy16(Kh + (size_t)(kt0 + r) * HD_ + cg * 8, (char*)&Ks[buf][0][0] + p);
    }
#pragma unroll
    for (int it = 0; it < 4; ++it) {
      int p = it * 4096 + tid * 16;
      int r = p >> 7;
      int cg = ((p >> 4) & 7) ^ (r & 7);
      async_copy16(Vh + (size_t)r * T_ + kt0 + cg * 8, (char*)&Vs[buf][0][0] + p);
    }
  };

  auto step = [&](int buf, const bf16x8* qf, floatx4* oacc, float& l_i, int q0, int kt0,
                  bool mask) {
    floatx4 s[4] = {{}, {}, {}, {}};
#pragma unroll
    for (int st = 0; st < 4; ++st) {
#pragma unroll
      for (int kk = 0; kk < 4; ++kk) {
        bf16x8 kf = *(const bf16x8*)&Ks[buf][st * 16 + l15][(((kk * 4 + quad) ^ l15) & 15) * 8];
        s[st] = __builtin_amdgcn_mfma_f32_16x16x32_bf16(kf, qf[kk], s[st], 0, 0, 0);
      }
    }
    float ps = 0.0f;
    long long pu[4];
#pragma unroll
    for (int st = 0; st < 4; ++st) {
      PU t;
#pragma unroll
      for (int r = 0; r < 4; ++r) {
        float val = s[st][r];
        if (mask) {
          int kt = kt0 + st * 16 + quad * 4 + r;
          val = (kt <= q0 + l15) ? val : -3.0e38f;
        }
        float p = exp2f(val);
        ps += p;
        t.v[r] = (bf16_t)p;
      }
      pu[st] = t.u;
    }
    ps += __shfl_xor(ps, 16);
    ps += __shfl_xor(ps, 32);
    l_i += ps;
#pragma unroll
    for (int bb = 0; bb < 2; ++bb) {
      long long lo0 = __shfl(pu[2 * bb], lo);
      long long hi0 = __shfl(pu[2 * bb], lo + 16);
      long long lo1 = __shfl(pu[2 * bb + 1], lo);
      long long hi1 = __shfl(pu[2 * bb + 1], lo + 16);
      PF pf;
      pf.u[0] = (quad >= 2) ? lo1 : lo0;
      pf.u[1] = (quad >= 2) ? hi1 : hi0;
#pragma unroll
      for (int dt = 0; dt < 8; ++dt) {
        bf16x8 vf = *(const bf16x8*)&Vs[buf][dt * 16 + l15][(((bb * 4 + quad) ^ l15) & 7) * 8];
        oacc[dt] = __builtin_amdgcn_mfma_f32_16x16x32_bf16(pf.v, vf, oacc[dt], 0, 0, 0);
      }
    }
  };

  stage(0, 0);
  for (int ch = 0; ch < nchA; ++ch) {
    __syncthreads();
    if (ch + 1 < nchA) stage((ch + 1) & 1, (ch + 1) * 64);  // fly during compute
    const int kt0 = ch * 64;
    const int buf = ch & 1;
    step(buf, qfA, oaccA, l_A, q0A, kt0, ch == nchA - 1);
    if (ch < nchB) step(buf, qfB, oaccB, l_B, q0B, kt0, ch == nchB - 1);
  }

  float lrA[4], lrB[4];
#pragma unroll
  for (int r = 0; r < 4; ++r) {
    lrA[r] = __shfl(l_A, quad * 4 + r);
    lrB[r] = __shfl(l_B, quad * 4 + r);
  }
#pragma unroll
  for (int dt = 0; dt < 8; ++dt) {
#pragma unroll
    for (int r = 0; r < 4; ++r) {
      int d = dt * 16 + l15;
      int qa = q0A + quad * 4 + r;
      int qb = q0B + quad * 4 + r;
      O[((size_t)(b * T_ + qa)) * C_ + h * HD_ + d] = (bf16_t)(oaccA[dt][r] / lrA[r]);
      O[((size_t)(b * T_ + qb)) * C_ + h * HD_ + d] = (bf16_t)(oaccB[dt][r] / lrB[r]);
    }
  }
}

// ---------------- launch ----------------
extern "C" void kernel_launch(void* const* d_in, const int* in_sizes, int n_in,
                              void* d_out, int out_size, void* d_ws, size_t ws_size,
                              hipStream_t stream) {
  const float* x      = (const float*)d_in[0];
  const float* w_attn = (const float*)d_in[1];
  const float* b_attn = (const float*)d_in[2];
  const float* w_proj = (const float*)d_in[3];
  const float* b_proj = (const float*)d_in[4];
  float* out = (float*)d_out;

  char* p = (char*)d_ws;
  bf16_t* xb  = (bf16_t*)p; p += (size_t)4096 * 2048 * 2;      // x bf16 [B*T][C]
  bf16_t* waT = (bf16_t*)p; p += (size_t)6144 * 2048 * 2;      // w_attn^T bf16 [3C][C]
  bf16_t* wpT = (bf16_t*)p; p += (size_t)2048 * 2048 * 2;      // w_proj^T bf16 [C][C]
  bf16_t* Qb  = (bf16_t*)p; p += (size_t)32 * 2048 * 128 * 2;  // [B,H,T,hd] (pre-scaled)
  bf16_t* Kb  = (bf16_t*)p; p += (size_t)32 * 2048 * 128 * 2;  // [B,H,T,hd]
  bf16_t* Vb  = (bf16_t*)p; p += (size_t)32 * 2048 * 128 * 2;  // [B,H,hd,T] (transposed)
  bf16_t* Ob  = (bf16_t*)p; p += (size_t)4096 * 2048 * 2;      // attn out bf16 [B*T][C]

  cvt_f32_bf16<<<8192, 256, 0, stream>>>(x, xb, 2097152);
  transpose_cvt<<<dim3(6144 / 32, 2048 / 32), dim3(32, 8), 0, stream>>>(w_attn, waT, 2048, 6144);
  transpose_cvt<<<dim3(2048 / 32, 2048 / 32), dim3(32, 8), 0, stream>>>(w_proj, wpT, 2048, 2048);

  gemm_qkv<<<dim3(6144 / GBN, 4096 / GBM), 512, 0, stream>>>(
      xb, waT, b_attn, Qb, Kb, Vb, 2048);

  attn<<<dim3(16, 32), 256, 0, stream>>>(Qb, Kb, Vb, Ob);

  gemm_proj<<<dim3(2048 / TN, 4096 / TM), 256, 0, stream>>>(
      Ob, wpT, b_proj, out, 4096, 2048, 2048);
}